// Round 14
// baseline (5335.466 us; speedup 1.0000x reference)
//
#include <hip/hip_runtime.h>
#include <hip/hip_fp16.h>
#include <cstdint>
#include <cstddef>

#define B_ 64
#define S_ 2048
#define H_ 256
#define E_ 256
#define NG 1024  // 4*H

typedef __attribute__((ext_vector_type(8))) short short8v;
typedef __attribute__((ext_vector_type(4))) float float4v;
typedef __fp16 half2v __attribute__((ext_vector_type(2)));

__device__ __forceinline__ short f2bf(float f) {
  uint32_t u = __float_as_uint(f);
  u = (u + 0x7fffu + ((u >> 16) & 1u)) >> 16;
  return (short)u;
}
__device__ __forceinline__ float sigf(float x) { return 1.f / (1.f + __expf(-x)); }
__device__ __forceinline__ float tanhf_fast(float x) {
  float ax = fabsf(x);
  float e = __expf(-2.f * ax);  // in (0,1], never overflows
  float t = (1.f - e) / (1.f + e);
  return copysignf(t, x);
}
__device__ __forceinline__ uint32_t pkh2(float a, float b) {
  return __builtin_bit_cast(uint32_t, __floats2half2_rn(a, b));
}

// f16-pair dot product with f32 accumulate (v_dot2_f32_f16).
__device__ __forceinline__ float dot2f(uint32_t w, uint32_t h, float acc) {
#if __has_builtin(__builtin_amdgcn_fdot2)
  return __builtin_amdgcn_fdot2(__builtin_bit_cast(half2v, w),
                                __builtin_bit_cast(half2v, h), acc, false);
#else
  __half2 hw = __builtin_bit_cast(__half2, w);
  __half2 hh = __builtin_bit_cast(__half2, h);
  acc = fmaf(__half2float(hw.x), __half2float(hh.x), acc);
  acc = fmaf(__half2float(hw.y), __half2float(hh.y), acc);
  return acc;
#endif
}

// Reduce across lane-bit3 (row_ror:8) and lane-bit5 (permlane32_swap).
// Result valid in ALL lanes. Pure VALU. (R6-R12 validated.)
__device__ __forceinline__ float red_q4(float x) {
  x += __builtin_bit_cast(float, __builtin_amdgcn_update_dpp(
           0, __builtin_bit_cast(int, x), 0x128, 0xf, 0xf, true));  // row_ror:8
  float a = x, b = x;
  asm("v_permlane32_swap_b32 %0, %1" : "+v"(a), "+v"(b));
  return a + b;
}

// Light workgroup barrier: drains ONLY LDS ops (h ping-pong visibility),
// not vmcnt — the per-step global out-store flies across steps. (R12.)
#define SYNC_LDS() asm volatile("s_waitcnt lgkmcnt(0)\n\ts_barrier" ::: "memory")

// ---------------------------------------------------------------------------
// Phase 1: gate preactivations  pre[m][j] = emb_z[idx[m]] . W_g[j] + b_i + b_h
// M = 64*Cc rows (m = b*Cc + s_local), N = 1024, K = 256. bf16 MFMA 16x16x32.
// Output stored f16.
// ---------------------------------------------------------------------------
__global__ __launch_bounds__(256, 2)
void lstm_xproj(const int* __restrict__ idx, const float* __restrict__ emb,
                const float* __restrict__ w0, const float* __restrict__ w1,
                const float* __restrict__ w2, const float* __restrict__ w3,
                const float* __restrict__ bi0, const float* __restrict__ bi1,
                const float* __restrict__ bi2, const float* __restrict__ bi3,
                const float* __restrict__ bh0, const float* __restrict__ bh1,
                const float* __restrict__ bh2, const float* __restrict__ bh3,
                __half* __restrict__ pre, int s0, int Cc) {
  __shared__ __align__(16) short Ak[4][128][8];  // [kseg][row][8 contiguous k]
  __shared__ __align__(16) short Bk[4][128][8];
  __shared__ int ridx[128];

  const int tid = threadIdx.x;
  const int bm = blockIdx.x, bn = blockIdx.y;
  const int n0 = bn * 128;
  const int g = bn >> 1;            // gate (0..3)
  const int ng = (bn & 1) * 128;    // row base within gate
  const float* wp  = (g == 0) ? w0  : (g == 1) ? w1  : (g == 2) ? w2  : w3;
  const float* bip = (g == 0) ? bi0 : (g == 1) ? bi1 : (g == 2) ? bi2 : bi3;
  const float* bhp = (g == 0) ? bh0 : (g == 1) ? bh1 : (g == 2) ? bh2 : bh3;

  if (tid < 128) {
    int m = bm * 128 + tid;
    int bb = m / Cc;
    int ss = m - bb * Cc;
    ridx[tid] = idx[bb * S_ + s0 + ss];
  }

  float4v z = {0.f, 0.f, 0.f, 0.f};
  float4v acc[4][4];
#pragma unroll
  for (int mi = 0; mi < 4; ++mi)
#pragma unroll
    for (int ni = 0; ni < 4; ++ni) acc[mi][ni] = z;

  const int wv = tid >> 6, lane = tid & 63;
  const int wr = wv >> 1, wc = wv & 1;
  const int lr = lane & 15, ks = lane >> 4;
  const int sr = tid >> 3, seg = tid & 7;

  for (int kt = 0; kt < 8; ++kt) {
    const int k0 = kt * 32;
    __syncthreads();
#pragma unroll
    for (int it = 0; it < 4; ++it) {
      int r = sr + it * 32;
      int tok = ridx[r];
      float4 va = make_float4(0.f, 0.f, 0.f, 0.f);
      if (tok != 0) va = *(const float4*)(emb + (size_t)tok * E_ + k0 + seg * 4);
      short4 sa; sa.x = f2bf(va.x); sa.y = f2bf(va.y); sa.z = f2bf(va.z); sa.w = f2bf(va.w);
      *(short4*)&Ak[seg >> 1][r][(seg & 1) * 4] = sa;
      float4 vb = *(const float4*)(wp + (size_t)(ng + r) * E_ + k0 + seg * 4);
      short4 sb; sb.x = f2bf(vb.x); sb.y = f2bf(vb.y); sb.z = f2bf(vb.z); sb.w = f2bf(vb.w);
      *(short4*)&Bk[seg >> 1][r][(seg & 1) * 4] = sb;
    }
    __syncthreads();
    short8v af[4], bfv[4];
#pragma unroll
    for (int mi = 0; mi < 4; ++mi) af[mi] = *(short8v*)&Ak[ks][wr * 64 + mi * 16 + lr][0];
#pragma unroll
    for (int ni = 0; ni < 4; ++ni) bfv[ni] = *(short8v*)&Bk[ks][wc * 64 + ni * 16 + lr][0];
#pragma unroll
    for (int mi = 0; mi < 4; ++mi)
#pragma unroll
      for (int ni = 0; ni < 4; ++ni)
        acc[mi][ni] = __builtin_amdgcn_mfma_f32_16x16x32_bf16(af[mi], bfv[ni], acc[mi][ni], 0, 0, 0);
  }

#pragma unroll
  for (int ni = 0; ni < 4; ++ni) {
    int jj = ng + wc * 64 + ni * 16 + lr;
    float bias = bip[jj] + bhp[jj];
    int jglob = n0 + wc * 64 + ni * 16 + lr;
#pragma unroll
    for (int mi = 0; mi < 4; ++mi) {
#pragma unroll
      for (int rr = 0; rr < 4; ++rr) {
        int m = bm * 128 + wr * 64 + mi * 16 + (lane >> 4) * 4 + rr;
        pre[(size_t)m * NG + jglob] = __float2half(acc[mi][ni][rr] + bias);
      }
    }
  }
}

// ---------------------------------------------------------------------------
// Phase 2: recurrence. R14: 64 WGs x 1024 threads (16 waves = 4 waves/SIMD,
// 2x the TLP of R12 — the measured stall was idle-pipe latency at 2 w/SIMD).
// Thread (j, q4) owns ONE output row j (0..255) over K-quarter q4 for all 4
// gates: archival i/f/g = 96 dwords/thread -> fits the 128-reg budget at
// 4 waves/SIMD (launch_bounds(1024,4), static 128 KB LDS keeps 1 WG/CU).
// Lane layout unchanged (q4 on bits 3/5 -> red_q4 identical); o-LDS layout
// byte-pattern identical to R12's proven 0-conflict swizzle (key row&7,
// since rows are now per-thread). Ping-pong h + light barrier (R10/R12).
// ---------------------------------------------------------------------------
__global__ __launch_bounds__(1024, 4)
void lstm_rec(const __half* __restrict__ pre,
              const float* wh_i, const float* wh_f,
              const float* wh_g, const float* wh_o,
              const float* __restrict__ h0, const float* __restrict__ c0,
              float* out, float* cstate,
              int s0, int Cc) {
  __shared__ uint32_t wlds32[256 * 128];  // o-gate f16 pairs (swizzled), 128 KB
  __shared__ uint32_t hshp[288];          // 2 x 144 quarter-padded f16 h pairs

  const int b = blockIdx.x;
  const int t = threadIdx.x;
  const int lane = t & 63, wave = t >> 6;
  const int q4 = ((lane >> 3) & 1) | ((lane >> 5) << 1);               // 0..3
  const int j = (wave << 4) | (((lane >> 4) & 1) << 3) | (lane & 7);   // 0..255
  const bool fin = ((lane & 40) == 0);   // q4 == 0: lanes 0-7, 16-23
  const int sw = (j & 7) << 2;           // o-row XOR swizzle (dwords)

  // --- stage o-gate into LDS, swizzled: col' = col ^ ((row&7)<<2) ---
#pragma unroll 8
  for (int i = 0; i < 32; ++i) {
    int d = t + 1024 * i;
    int row = d >> 7, col = d & 127;
    float2 v = *(const float2*)(wh_o + 2 * (size_t)d);
    wlds32[row * 128 + (col ^ ((row & 7) << 2))] = pkh2(v.x, v.y);
  }

  // --- stage i,f,g row j, K in [64*q4, 64*q4+64) into registers (96 dw) ---
  uint32_t wI[32], wF[32], wG[32];
  {
    const float4* pI = (const float4*)(wh_i + (size_t)j * 256 + q4 * 64);
    const float4* pF = (const float4*)(wh_f + (size_t)j * 256 + q4 * 64);
    const float4* pG = (const float4*)(wh_g + (size_t)j * 256 + q4 * 64);
#pragma unroll
    for (int k = 0; k < 16; ++k) {
      float4 v;
      v = pI[k]; wI[2 * k] = pkh2(v.x, v.y); wI[2 * k + 1] = pkh2(v.z, v.w);
      v = pF[k]; wF[2 * k] = pkh2(v.x, v.y); wF[2 * k + 1] = pkh2(v.z, v.w);
      v = pG[k]; wG[2 * k] = pkh2(v.x, v.y); wG[2 * k + 1] = pkh2(v.z, v.w);
    }
  }

  // --- init h (buf0) and c (registers, fin lanes) ---
  if (t < 128) {
    float2 hp = (s0 == 0) ? *(const float2*)(h0 + b * H_ + 2 * t)
                          : *(const float2*)(cstate + b * 512 + 256 + 2 * t);
    hshp[(t >> 5) * 36 + (t & 31)] = pkh2(hp.x, hp.y);
  }
  float cR = 0.f, hN = 0.f;
  if (fin) cR = (s0 == 0) ? c0[b * H_ + j] : cstate[b * 512 + j];
  __syncthreads();   // staging + h-init complete (full drain once is fine)

  const __half* pb16 = pre + (size_t)b * (size_t)Cc * NG;
  const uint32_t* wrow = wlds32 + (size_t)j * 128 + q4 * 32;
  const uint32_t* hqA = hshp + q4 * 36;          // read buf0
  const uint32_t* hqB = hqA + 144;               // read buf1
  const int jp = j >> 1;
  uint16_t* hwB = (uint16_t*)(hshp + (jp >> 5) * 36 + (jp & 31)) + (j & 1);
  uint16_t* hwA = hwB + 288;                     // +144 dwords = buf1
  float* outp = out + ((size_t)b * S_ + s0) * H_ + j;

#define HV_(c8)  (*(const uint4*)(hq + (c8) * 4))
#define WO_(c8)  (*(const uint4*)(wrow + (((c8) * 4) ^ sw)))
#define STG_(c8, hv, wa)                                        \
  aO = dot2f(wa.x, hv.x, aO); aO = dot2f(wa.y, hv.y, aO);       \
  aO = dot2f(wa.z, hv.z, aO); aO = dot2f(wa.w, hv.w, aO);       \
  aI = dot2f(wI[(c8) * 4 + 0], hv.x, aI);                       \
  aI = dot2f(wI[(c8) * 4 + 1], hv.y, aI);                       \
  aI = dot2f(wI[(c8) * 4 + 2], hv.z, aI);                       \
  aI = dot2f(wI[(c8) * 4 + 3], hv.w, aI);                       \
  aF = dot2f(wF[(c8) * 4 + 0], hv.x, aF);                       \
  aF = dot2f(wF[(c8) * 4 + 1], hv.y, aF);                       \
  aF = dot2f(wF[(c8) * 4 + 2], hv.z, aF);                       \
  aF = dot2f(wF[(c8) * 4 + 3], hv.w, aF);                       \
  aG = dot2f(wG[(c8) * 4 + 0], hv.x, aG);                       \
  aG = dot2f(wG[(c8) * 4 + 1], hv.y, aG);                       \
  aG = dot2f(wG[(c8) * 4 + 2], hv.z, aG);                       \
  aG = dot2f(wG[(c8) * 4 + 3], hv.w, aG);

// One full LSTM step reading h from HQ, writing new h (u16) to HW.
#define BODY_(HQ, HW)                                                       \
  {                                                                         \
    float pIv = 0.f, pFv = 0.f, pGv = 0.f, pOv = 0.f;                       \
    if (fin) {                                                              \
      const __half* pp = pb16 + (size_t)tl * NG + j;                        \
      pIv = __half2float(pp[0]);                                            \
      pFv = __half2float(pp[256]);                                          \
      pGv = __half2float(pp[512]);                                          \
      pOv = __half2float(pp[768]);                                          \
    }                                                                       \
    const uint32_t* hq = (HQ);                                              \
    float aI = 0.f, aF = 0.f, aG = 0.f, aO = 0.f;                           \
    {                                                                       \
      uint4 hvA = HV_(0), waA = WO_(0);                                     \
      uint4 hvB = HV_(1), waB = WO_(1);                                     \
      STG_(0, hvA, waA); hvA = HV_(2); waA = WO_(2);                        \
      STG_(1, hvB, waB); hvB = HV_(3); waB = WO_(3);                        \
      STG_(2, hvA, waA); hvA = HV_(4); waA = WO_(4);                        \
      STG_(3, hvB, waB); hvB = HV_(5); waB = WO_(5);                        \
      STG_(4, hvA, waA); hvA = HV_(6); waA = WO_(6);                        \
      STG_(5, hvB, waB); hvB = HV_(7); waB = WO_(7);                        \
      STG_(6, hvA, waA);                                                    \
      STG_(7, hvB, waB);                                                    \
    }                                                                       \
    aI = red_q4(aI); aF = red_q4(aF);                                       \
    aG = red_q4(aG); aO = red_q4(aO);                                       \
    if (fin) {                                                              \
      float xi = aI + pIv, xf = aF + pFv;                                   \
      float xg = aG + pGv, xo = aO + pOv;                                   \
      cR = sigf(xf) * cR + sigf(xi) * tanhf_fast(xg);                       \
      hN = sigf(xo) * tanhf_fast(cR);                                       \
      *outp = hN;                                                           \
      *(HW) = (uint16_t)(pkh2(hN, 0.f) & 0xffffu);                          \
    }                                                                       \
    outp += H_;                                                             \
    ++tl;                                                                   \
    SYNC_LDS();                                                             \
  }

  int tl = 0;
  while (tl < Cc) {       // Cc is even (launcher guarantees)
    BODY_(hqA, hwA);      // reads buf0, writes buf1
    BODY_(hqB, hwB);      // reads buf1, writes buf0
  }
#undef BODY_
#undef STG_
#undef WO_
#undef HV_

  if (fin) {
    cstate[b * 512 + j] = cR;
    cstate[b * 512 + 256 + j] = hN;
    if (s0 + Cc == S_) {
      float* hfp = out + (size_t)B_ * S_ * H_;
      float* cfp = hfp + (size_t)B_ * H_;
      hfp[b * H_ + j] = hN;
      cfp[b * H_ + j] = cR;
    }
  }
}

// ---------------------------------------------------------------------------
extern "C" void kernel_launch(void* const* d_in, const int* in_sizes, int n_in,
                              void* d_out, int out_size, void* d_ws, size_t ws_size,
                              hipStream_t stream) {
  (void)in_sizes; (void)n_in; (void)out_size;
  const int* idx = (const int*)d_in[0];
  const float* h0 = (const float*)d_in[1];
  const float* c0 = (const float*)d_in[2];
  const float* emb = (const float*)d_in[3];
  const float* w_ii = (const float*)d_in[4];
  const float* w_if = (const float*)d_in[5];
  const float* w_ig = (const float*)d_in[6];
  const float* w_io = (const float*)d_in[7];
  const float* w_hi = (const float*)d_in[8];
  const float* w_hf = (const float*)d_in[9];
  const float* w_hg = (const float*)d_in[10];
  const float* w_ho = (const float*)d_in[11];
  const float* b_ii = (const float*)d_in[12];
  const float* b_if = (const float*)d_in[13];
  const float* b_ig = (const float*)d_in[14];
  const float* b_io = (const float*)d_in[15];
  const float* b_hi = (const float*)d_in[16];
  const float* b_hf = (const float*)d_in[17];
  const float* b_hg = (const float*)d_in[18];
  const float* b_ho = (const float*)d_in[19];
  float* out = (float*)d_out;

  char* ws = (char*)d_ws;
  float* cstate = (float*)ws;                 // 64 * 512 * 4 = 128 KB (c | h)
  __half* pre = (__half*)(ws + 131072);       // rest: f16 preactivations
  size_t avail = (ws_size > 131072) ? ws_size - 131072 : 0;
  long long cmax = (long long)(avail / ((size_t)B_ * NG * sizeof(__half)));
  int C = (int)((cmax > S_) ? S_ : cmax);
  C &= ~1;
  if (C < 2) C = 2;

  for (int s0 = 0; s0 < S_; s0 += C) {
    int Cc = (S_ - s0 < C) ? (S_ - s0) : C;
    dim3 gg((unsigned)((64 * Cc) / 128), 8);
    lstm_xproj<<<gg, 256, 0, stream>>>(idx, emb, w_ii, w_if, w_ig, w_io,
                                       b_ii, b_if, b_ig, b_io,
                                       b_hi, b_hf, b_hg, b_ho, pre, s0, Cc);
    lstm_rec<<<64, 1024, 0, stream>>>(pre, w_hi, w_hf, w_hg, w_ho, h0, c0,
                                      out, cstate, s0, Cc);
  }
}

// Round 15
// 4493.982 us; speedup vs baseline: 1.1872x; 1.1872x over previous
//
#include <hip/hip_runtime.h>
#include <hip/hip_fp16.h>
#include <cstdint>
#include <cstddef>

#define B_ 64
#define S_ 2048
#define H_ 256
#define E_ 256
#define NG 1024  // 4*H

typedef __attribute__((ext_vector_type(8))) short short8v;
typedef __attribute__((ext_vector_type(4))) float float4v;
typedef __fp16 half2v __attribute__((ext_vector_type(2)));

__device__ __forceinline__ short f2bf(float f) {
  uint32_t u = __float_as_uint(f);
  u = (u + 0x7fffu + ((u >> 16) & 1u)) >> 16;
  return (short)u;
}
__device__ __forceinline__ float sigf(float x) { return 1.f / (1.f + __expf(-x)); }
__device__ __forceinline__ float tanhf_fast(float x) {
  float ax = fabsf(x);
  float e = __expf(-2.f * ax);  // in (0,1], never overflows
  float t = (1.f - e) / (1.f + e);
  return copysignf(t, x);
}
__device__ __forceinline__ uint32_t pkh2(float a, float b) {
  return __builtin_bit_cast(uint32_t, __floats2half2_rn(a, b));
}

// f16-pair dot product with f32 accumulate — FORCED to the hardware
// v_dot2_f32_f16 (1 inst / 2 MACs). R12's builtin/fallback path compiled to
// multi-inst sequences (~990 VALU insts/thread/step measured vs ~370 needed;
// active-CU VALUBusy 87% -> issue-bound on expanded dot code).
__device__ __forceinline__ float dot2f(uint32_t w, uint32_t h, float acc) {
  float d;
  asm("v_dot2_f32_f16 %0, %1, %2, %3" : "=v"(d) : "v"(w), "v"(h), "v"(acc));
  return d;
}

// Reduce across lane-bit3 (row_ror:8) and lane-bit5 (permlane32_swap).
// Result valid in ALL lanes. Pure VALU. (R6-R12 validated.)
__device__ __forceinline__ float red_q4(float x) {
  x += __builtin_bit_cast(float, __builtin_amdgcn_update_dpp(
           0, __builtin_bit_cast(int, x), 0x128, 0xf, 0xf, true));  // row_ror:8
  float a = x, b = x;
  asm("v_permlane32_swap_b32 %0, %1" : "+v"(a), "+v"(b));
  return a + b;
}

// Light workgroup barrier: drains ONLY LDS ops (h ping-pong visibility),
// not vmcnt — the per-step global out-store flies across steps. (R12.)
#define SYNC_LDS() asm volatile("s_waitcnt lgkmcnt(0)\n\ts_barrier" ::: "memory")

// ---------------------------------------------------------------------------
// Phase 1: gate preactivations  pre[m][j] = emb_z[idx[m]] . W_g[j] + b_i + b_h
// M = 64*Cc rows (m = b*Cc + s_local), N = 1024, K = 256. bf16 MFMA 16x16x32.
// Output stored f16.
// ---------------------------------------------------------------------------
__global__ __launch_bounds__(256, 2)
void lstm_xproj(const int* __restrict__ idx, const float* __restrict__ emb,
                const float* __restrict__ w0, const float* __restrict__ w1,
                const float* __restrict__ w2, const float* __restrict__ w3,
                const float* __restrict__ bi0, const float* __restrict__ bi1,
                const float* __restrict__ bi2, const float* __restrict__ bi3,
                const float* __restrict__ bh0, const float* __restrict__ bh1,
                const float* __restrict__ bh2, const float* __restrict__ bh3,
                __half* __restrict__ pre, int s0, int Cc) {
  __shared__ __align__(16) short Ak[4][128][8];  // [kseg][row][8 contiguous k]
  __shared__ __align__(16) short Bk[4][128][8];
  __shared__ int ridx[128];

  const int tid = threadIdx.x;
  const int bm = blockIdx.x, bn = blockIdx.y;
  const int n0 = bn * 128;
  const int g = bn >> 1;            // gate (0..3)
  const int ng = (bn & 1) * 128;    // row base within gate
  const float* wp  = (g == 0) ? w0  : (g == 1) ? w1  : (g == 2) ? w2  : w3;
  const float* bip = (g == 0) ? bi0 : (g == 1) ? bi1 : (g == 2) ? bi2 : bi3;
  const float* bhp = (g == 0) ? bh0 : (g == 1) ? bh1 : (g == 2) ? bh2 : bh3;

  if (tid < 128) {
    int m = bm * 128 + tid;
    int bb = m / Cc;
    int ss = m - bb * Cc;
    ridx[tid] = idx[bb * S_ + s0 + ss];
  }

  float4v z = {0.f, 0.f, 0.f, 0.f};
  float4v acc[4][4];
#pragma unroll
  for (int mi = 0; mi < 4; ++mi)
#pragma unroll
    for (int ni = 0; ni < 4; ++ni) acc[mi][ni] = z;

  const int wv = tid >> 6, lane = tid & 63;
  const int wr = wv >> 1, wc = wv & 1;
  const int lr = lane & 15, ks = lane >> 4;
  const int sr = tid >> 3, seg = tid & 7;

  for (int kt = 0; kt < 8; ++kt) {
    const int k0 = kt * 32;
    __syncthreads();
#pragma unroll
    for (int it = 0; it < 4; ++it) {
      int r = sr + it * 32;
      int tok = ridx[r];
      float4 va = make_float4(0.f, 0.f, 0.f, 0.f);
      if (tok != 0) va = *(const float4*)(emb + (size_t)tok * E_ + k0 + seg * 4);
      short4 sa; sa.x = f2bf(va.x); sa.y = f2bf(va.y); sa.z = f2bf(va.z); sa.w = f2bf(va.w);
      *(short4*)&Ak[seg >> 1][r][(seg & 1) * 4] = sa;
      float4 vb = *(const float4*)(wp + (size_t)(ng + r) * E_ + k0 + seg * 4);
      short4 sb; sb.x = f2bf(vb.x); sb.y = f2bf(vb.y); sb.z = f2bf(vb.z); sb.w = f2bf(vb.w);
      *(short4*)&Bk[seg >> 1][r][(seg & 1) * 4] = sb;
    }
    __syncthreads();
    short8v af[4], bfv[4];
#pragma unroll
    for (int mi = 0; mi < 4; ++mi) af[mi] = *(short8v*)&Ak[ks][wr * 64 + mi * 16 + lr][0];
#pragma unroll
    for (int ni = 0; ni < 4; ++ni) bfv[ni] = *(short8v*)&Bk[ks][wc * 64 + ni * 16 + lr][0];
#pragma unroll
    for (int mi = 0; mi < 4; ++mi)
#pragma unroll
      for (int ni = 0; ni < 4; ++ni)
        acc[mi][ni] = __builtin_amdgcn_mfma_f32_16x16x32_bf16(af[mi], bfv[ni], acc[mi][ni], 0, 0, 0);
  }

#pragma unroll
  for (int ni = 0; ni < 4; ++ni) {
    int jj = ng + wc * 64 + ni * 16 + lr;
    float bias = bip[jj] + bhp[jj];
    int jglob = n0 + wc * 64 + ni * 16 + lr;
#pragma unroll
    for (int mi = 0; mi < 4; ++mi) {
#pragma unroll
      for (int rr = 0; rr < 4; ++rr) {
        int m = bm * 128 + wr * 64 + mi * 16 + (lane >> 4) * 4 + rr;
        pre[(size_t)m * NG + jglob] = __float2half(acc[mi][ni][rr] + bias);
      }
    }
  }
}

// ---------------------------------------------------------------------------
// Phase 2: recurrence. One WG per batch element: 64 WGs x 512 threads,
// static ~129 KB LDS (1 WG/CU, 2 waves/SIMD, 256 V+A regs/wave).
// Thread (jp,q4) owns output rows j0=2jp,j0+1 over K-quarter q4 for all 4
// gates (R8/R10/R12-validated structure). R15 change (single, isolated):
// dot2f is inline-asm v_dot2_f32_f16 — see dot2f comment.
// ---------------------------------------------------------------------------
__global__ __launch_bounds__(512, 2)
void lstm_rec(const __half* __restrict__ pre,
              const float* wh_i, const float* wh_f,
              const float* wh_g, const float* wh_o,
              const float* __restrict__ h0, const float* __restrict__ c0,
              float* out, float* cstate,
              int s0, int Cc) {
  __shared__ uint32_t wlds32[256 * 128];  // o-gate packed f16 pairs (swizzled)
  __shared__ uint32_t hshp[288];          // 2 x 144 quarter-padded h pairs

  const int b = blockIdx.x;
  const int t = threadIdx.x;
  const int lane = t & 63, wave = t >> 6;
  const int q4 = ((lane >> 3) & 1) | ((lane >> 5) << 1);               // 0..3
  const int jp = (wave << 4) | (((lane >> 4) & 1) << 3) | (lane & 7);  // 0..127
  const int j0 = 2 * jp;
  const bool fin = ((lane & 40) == 0);   // q4 == 0: lanes 0-7, 16-23
  const int sw = (jp & 7) << 2;          // o-row XOR swizzle (dwords)

  // --- stage o-gate into LDS, swizzled: col' = col ^ ((row>>1 & 7)<<2) ---
#pragma unroll 8
  for (int i = 0; i < 64; ++i) {
    int idx2 = t + 512 * i;
    int row = idx2 >> 7, col = idx2 & 127;
    float2 v = *(const float2*)(wh_o + 2 * idx2);
    wlds32[row * 128 + (col ^ (((row >> 1) & 7) << 2))] = pkh2(v.x, v.y);
  }

  // --- stage i,f,g rows j0, j0+1, K in [64*q4, 64*q4+64) into registers ---
  uint32_t wI0[32], wI1[32], wF0[32], wF1[32], wG0[32], wG1[32];
  {
    const float4* pI0 = (const float4*)(wh_i + (size_t)j0 * 256 + q4 * 64);
    const float4* pI1 = (const float4*)(wh_i + (size_t)(j0 + 1) * 256 + q4 * 64);
    const float4* pF0 = (const float4*)(wh_f + (size_t)j0 * 256 + q4 * 64);
    const float4* pF1 = (const float4*)(wh_f + (size_t)(j0 + 1) * 256 + q4 * 64);
    const float4* pG0 = (const float4*)(wh_g + (size_t)j0 * 256 + q4 * 64);
    const float4* pG1 = (const float4*)(wh_g + (size_t)(j0 + 1) * 256 + q4 * 64);
#pragma unroll
    for (int k = 0; k < 16; ++k) {
      float4 v;
      v = pI0[k]; wI0[2 * k] = pkh2(v.x, v.y); wI0[2 * k + 1] = pkh2(v.z, v.w);
      v = pI1[k]; wI1[2 * k] = pkh2(v.x, v.y); wI1[2 * k + 1] = pkh2(v.z, v.w);
      v = pF0[k]; wF0[2 * k] = pkh2(v.x, v.y); wF0[2 * k + 1] = pkh2(v.z, v.w);
      v = pF1[k]; wF1[2 * k] = pkh2(v.x, v.y); wF1[2 * k + 1] = pkh2(v.z, v.w);
      v = pG0[k]; wG0[2 * k] = pkh2(v.x, v.y); wG0[2 * k + 1] = pkh2(v.z, v.w);
      v = pG1[k]; wG1[2 * k] = pkh2(v.x, v.y); wG1[2 * k + 1] = pkh2(v.z, v.w);
    }
  }

  // --- init h (buf0) and c (registers, fin lanes) ---
  if (t < 128) {
    float2 hp = (s0 == 0) ? *(const float2*)(h0 + b * H_ + 2 * t)
                          : *(const float2*)(cstate + b * 512 + 256 + 2 * t);
    hshp[(t >> 5) * 36 + (t & 31)] = pkh2(hp.x, hp.y);
  }
  float cR0 = 0.f, cR1 = 0.f, hN0 = 0.f, hN1 = 0.f;
  if (fin) {
    float2 cv = (s0 == 0) ? *(const float2*)(c0 + b * H_ + j0)
                          : *(const float2*)(cstate + b * 512 + j0);
    cR0 = cv.x; cR1 = cv.y;
  }
  __syncthreads();   // staging + h-init complete (full drain once is fine)

  const uint32_t* pb32 = (const uint32_t*)(pre + (size_t)b * (size_t)Cc * NG);
  const uint32_t* wrow0 = wlds32 + (size_t)j0 * 128 + q4 * 32;
  const uint32_t* wrow1 = wrow0 + 128;
  const uint32_t* hqA = hshp + q4 * 36;          // read buf0
  const uint32_t* hqB = hqA + 144;               // read buf1
  uint32_t* hwB = hshp + (jp >> 5) * 36 + (jp & 31);  // write buf0 (body B)
  uint32_t* hwA = hwB + 144;                          // write buf1 (body A)
  float* outp = out + ((size_t)b * S_ + s0) * H_ + j0;

#define HV_(c8)  (*(const uint4*)(hq + (c8) * 4))
#define WO0_(c8) (*(const uint4*)(wrow0 + (((c8) * 4) ^ sw)))
#define WO1_(c8) (*(const uint4*)(wrow1 + (((c8) * 4) ^ sw)))
#define CONS_(c8, hv, wa, wb)                                   \
  aO0 = dot2f(wa.x, hv.x, aO0); aO0 = dot2f(wa.y, hv.y, aO0);   \
  aO0 = dot2f(wa.z, hv.z, aO0); aO0 = dot2f(wa.w, hv.w, aO0);   \
  aO1 = dot2f(wb.x, hv.x, aO1); aO1 = dot2f(wb.y, hv.y, aO1);   \
  aO1 = dot2f(wb.z, hv.z, aO1); aO1 = dot2f(wb.w, hv.w, aO1);   \
  aI0 = dot2f(wI0[(c8) * 4 + 0], hv.x, aI0);                    \
  aI0 = dot2f(wI0[(c8) * 4 + 1], hv.y, aI0);                    \
  aI0 = dot2f(wI0[(c8) * 4 + 2], hv.z, aI0);                    \
  aI0 = dot2f(wI0[(c8) * 4 + 3], hv.w, aI0);                    \
  aI1 = dot2f(wI1[(c8) * 4 + 0], hv.x, aI1);                    \
  aI1 = dot2f(wI1[(c8) * 4 + 1], hv.y, aI1);                    \
  aI1 = dot2f(wI1[(c8) * 4 + 2], hv.z, aI1);                    \
  aI1 = dot2f(wI1[(c8) * 4 + 3], hv.w, aI1);                    \
  aF0 = dot2f(wF0[(c8) * 4 + 0], hv.x, aF0);                    \
  aF0 = dot2f(wF0[(c8) * 4 + 1], hv.y, aF0);                    \
  aF0 = dot2f(wF0[(c8) * 4 + 2], hv.z, aF0);                    \
  aF0 = dot2f(wF0[(c8) * 4 + 3], hv.w, aF0);                    \
  aF1 = dot2f(wF1[(c8) * 4 + 0], hv.x, aF1);                    \
  aF1 = dot2f(wF1[(c8) * 4 + 1], hv.y, aF1);                    \
  aF1 = dot2f(wF1[(c8) * 4 + 2], hv.z, aF1);                    \
  aF1 = dot2f(wF1[(c8) * 4 + 3], hv.w, aF1);                    \
  aG0 = dot2f(wG0[(c8) * 4 + 0], hv.x, aG0);                    \
  aG0 = dot2f(wG0[(c8) * 4 + 1], hv.y, aG0);                    \
  aG0 = dot2f(wG0[(c8) * 4 + 2], hv.z, aG0);                    \
  aG0 = dot2f(wG0[(c8) * 4 + 3], hv.w, aG0);                    \
  aG1 = dot2f(wG1[(c8) * 4 + 0], hv.x, aG1);                    \
  aG1 = dot2f(wG1[(c8) * 4 + 1], hv.y, aG1);                    \
  aG1 = dot2f(wG1[(c8) * 4 + 2], hv.z, aG1);                    \
  aG1 = dot2f(wG1[(c8) * 4 + 3], hv.w, aG1);

// One full LSTM step reading h from HQ, writing new h to HW (other buffer).
// Enters with waA/wbA = o-chunk0, waB/wbB = o-chunk1 already resident.
#define BODY_(HQ, HW)                                                       \
  {                                                                         \
    uint32_t pC0 = 0, pC1 = 0, pC2 = 0, pC3 = 0;                            \
    if (fin) {                                                              \
      const uint32_t* pp = pb32 + (size_t)tl * 512;                         \
      pC0 = pp[jp];       pC1 = pp[128 + jp];                               \
      pC2 = pp[256 + jp]; pC3 = pp[384 + jp];                               \
    }                                                                       \
    const uint32_t* hq = (HQ);                                              \
    float aI0 = 0.f, aI1 = 0.f, aF0 = 0.f, aF1 = 0.f;                       \
    float aG0 = 0.f, aG1 = 0.f, aO0 = 0.f, aO1 = 0.f;                       \
    {                                                                       \
      uint4 hvA = HV_(0), hvB = HV_(1), hvC = HV_(2);                       \
      CONS_(0, hvA, waA, wbA);                                              \
      waA = WO0_(2); wbA = WO1_(2); hvA = HV_(3);                           \
      CONS_(1, hvB, waB, wbB);                                              \
      waB = WO0_(3); wbB = WO1_(3); hvB = HV_(4);                           \
      CONS_(2, hvC, waA, wbA);                                              \
      waA = WO0_(4); wbA = WO1_(4); hvC = HV_(5);                           \
      CONS_(3, hvA, waB, wbB);                                              \
      waB = WO0_(5); wbB = WO1_(5); hvA = HV_(6);                           \
      CONS_(4, hvB, waA, wbA);                                              \
      waA = WO0_(6); wbA = WO1_(6); hvB = HV_(7);                           \
      CONS_(5, hvC, waB, wbB);                                              \
      waB = WO0_(7); wbB = WO1_(7);                                         \
      CONS_(6, hvA, waA, wbA);                                              \
      waA = WO0_(0); wbA = WO1_(0);        /* next-step o chunk 0 */        \
      CONS_(7, hvB, waB, wbB);                                              \
      waB = WO0_(1); wbB = WO1_(1);        /* next-step o chunk 1 */        \
    }                                                                       \
    aI0 = red_q4(aI0); aI1 = red_q4(aI1);                                   \
    aF0 = red_q4(aF0); aF1 = red_q4(aF1);                                   \
    aG0 = red_q4(aG0); aG1 = red_q4(aG1);                                   \
    aO0 = red_q4(aO0); aO1 = red_q4(aO1);                                   \
    if (fin) {                                                              \
      float2 pI = __half22float2(__builtin_bit_cast(__half2, pC0));         \
      float2 pF = __half22float2(__builtin_bit_cast(__half2, pC1));         \
      float2 pG = __half22float2(__builtin_bit_cast(__half2, pC2));         \
      float2 pO = __half22float2(__builtin_bit_cast(__half2, pC3));         \
      float xi0 = aI0 + pI.x, xi1 = aI1 + pI.y;                             \
      float xf0 = aF0 + pF.x, xf1 = aF1 + pF.y;                             \
      float xg0 = aG0 + pG.x, xg1 = aG1 + pG.y;                             \
      float xo0 = aO0 + pO.x, xo1 = aO1 + pO.y;                             \
      cR0 = sigf(xf0) * cR0 + sigf(xi0) * tanhf_fast(xg0);                  \
      cR1 = sigf(xf1) * cR1 + sigf(xi1) * tanhf_fast(xg1);                  \
      hN0 = sigf(xo0) * tanhf_fast(cR0);                                    \
      hN1 = sigf(xo1) * tanhf_fast(cR1);                                    \
      *(float2*)outp = make_float2(hN0, hN1);                               \
      *(HW) = pkh2(hN0, hN1);                                               \
    }                                                                       \
    outp += H_;                                                             \
    ++tl;                                                                   \
    SYNC_LDS();                                                             \
  }

  // prologue: o chunks 0/1 resident before the first body
  uint4 waA = WO0_(0), wbA = WO1_(0);
  uint4 waB = WO0_(1), wbB = WO1_(1);

  int tl = 0;
  while (tl < Cc) {       // Cc is even (launcher guarantees)
    BODY_(hqA, hwA);      // reads buf0, writes buf1
    BODY_(hqB, hwB);      // reads buf1, writes buf0
  }
#undef BODY_
#undef CONS_
#undef WO1_
#undef WO0_
#undef HV_

  if (fin) {
    *(float2*)(cstate + b * 512 + j0) = make_float2(cR0, cR1);
    *(float2*)(cstate + b * 512 + 256 + j0) = make_float2(hN0, hN1);
    if (s0 + Cc == S_) {
      float* hfp = out + (size_t)B_ * S_ * H_;
      float* cfp = hfp + (size_t)B_ * H_;
      *(float2*)(hfp + b * H_ + j0) = make_float2(hN0, hN1);
      *(float2*)(cfp + b * H_ + j0) = make_float2(cR0, cR1);
    }
  }
}

// ---------------------------------------------------------------------------
extern "C" void kernel_launch(void* const* d_in, const int* in_sizes, int n_in,
                              void* d_out, int out_size, void* d_ws, size_t ws_size,
                              hipStream_t stream) {
  (void)in_sizes; (void)n_in; (void)out_size;
  const int* idx = (const int*)d_in[0];
  const float* h0 = (const float*)d_in[1];
  const float* c0 = (const float*)d_in[2];
  const float* emb = (const float*)d_in[3];
  const float* w_ii = (const float*)d_in[4];
  const float* w_if = (const float*)d_in[5];
  const float* w_ig = (const float*)d_in[6];
  const float* w_io = (const float*)d_in[7];
  const float* w_hi = (const float*)d_in[8];
  const float* w_hf = (const float*)d_in[9];
  const float* w_hg = (const float*)d_in[10];
  const float* w_ho = (const float*)d_in[11];
  const float* b_ii = (const float*)d_in[12];
  const float* b_if = (const float*)d_in[13];
  const float* b_ig = (const float*)d_in[14];
  const float* b_io = (const float*)d_in[15];
  const float* b_hi = (const float*)d_in[16];
  const float* b_hf = (const float*)d_in[17];
  const float* b_hg = (const float*)d_in[18];
  const float* b_ho = (const float*)d_in[19];
  float* out = (float*)d_out;

  char* ws = (char*)d_ws;
  float* cstate = (float*)ws;                 // 64 * 512 * 4 = 128 KB (c | h)
  __half* pre = (__half*)(ws + 131072);       // rest: f16 preactivations
  size_t avail = (ws_size > 131072) ? ws_size - 131072 : 0;
  long long cmax = (long long)(avail / ((size_t)B_ * NG * sizeof(__half)));
  int C = (int)((cmax > S_) ? S_ : cmax);
  C &= ~1;
  if (C < 2) C = 2;

  for (int s0 = 0; s0 < S_; s0 += C) {
    int Cc = (S_ - s0 < C) ? (S_ - s0) : C;
    dim3 gg((unsigned)((64 * Cc) / 128), 8);
    lstm_xproj<<<gg, 256, 0, stream>>>(idx, emb, w_ii, w_if, w_ig, w_io,
                                       b_ii, b_if, b_ig, b_io,
                                       b_hi, b_hf, b_hg, b_ho, pre, s0, Cc);
    lstm_rec<<<64, 512, 0, stream>>>(pre, w_hi, w_hf, w_hg, w_ho, h0, c0,
                                     out, cstate, s0, Cc);
  }
}

// Round 16
// 4121.243 us; speedup vs baseline: 1.2946x; 1.0904x over previous
//
#include <hip/hip_runtime.h>
#include <hip/hip_fp16.h>
#include <cstdint>
#include <cstddef>

#define B_ 64
#define S_ 2048
#define H_ 256
#define E_ 256
#define NG 1024  // 4*H

typedef __attribute__((ext_vector_type(8))) short short8v;
typedef __attribute__((ext_vector_type(4))) float float4v;
typedef __fp16 half2v __attribute__((ext_vector_type(2)));

__device__ __forceinline__ short f2bf(float f) {
  uint32_t u = __float_as_uint(f);
  u = (u + 0x7fffu + ((u >> 16) & 1u)) >> 16;
  return (short)u;
}
__device__ __forceinline__ float sigf(float x) { return 1.f / (1.f + __expf(-x)); }
__device__ __forceinline__ float tanhf_fast(float x) {
  float ax = fabsf(x);
  float e = __expf(-2.f * ax);  // in (0,1], never overflows
  float t = (1.f - e) / (1.f + e);
  return copysignf(t, x);
}
__device__ __forceinline__ uint32_t pkh2(float a, float b) {
  return __builtin_bit_cast(uint32_t, __floats2half2_rn(a, b));
}

// f16-pair dot product with f32 accumulate (v_dot2_f32_f16).
// NOTE (R15 measured): the builtin path already emits the hardware dot;
// forcing inline asm REGRESSED 3.88->4.27 ms (blackbox blocks scheduling).
__device__ __forceinline__ float dot2f(uint32_t w, uint32_t h, float acc) {
#if __has_builtin(__builtin_amdgcn_fdot2)
  return __builtin_amdgcn_fdot2(__builtin_bit_cast(half2v, w),
                                __builtin_bit_cast(half2v, h), acc, false);
#else
  __half2 hw = __builtin_bit_cast(__half2, w);
  __half2 hh = __builtin_bit_cast(__half2, h);
  acc = fmaf(__half2float(hw.x), __half2float(hh.x), acc);
  acc = fmaf(__half2float(hw.y), __half2float(hh.y), acc);
  return acc;
#endif
}

// Reduce across lane-bit3 (row_ror:8) and lane-bit5 (permlane32_swap).
// Result valid in ALL lanes. Pure VALU — no LDS traffic. (R6-R12 validated.)
__device__ __forceinline__ float red_q4(float x) {
  x += __builtin_bit_cast(float, __builtin_amdgcn_update_dpp(
           0, __builtin_bit_cast(int, x), 0x128, 0xf, 0xf, true));  // row_ror:8
  float a = x, b = x;
  asm("v_permlane32_swap_b32 %0, %1" : "+v"(a), "+v"(b));
  return a + b;
}

// Light workgroup barrier: drains ONLY LDS ops (h ping-pong visibility),
// not vmcnt — the per-step global out-store flies across steps. (R12, +3%.)
#define SYNC_LDS() asm volatile("s_waitcnt lgkmcnt(0)\n\ts_barrier" ::: "memory")

// ---------------------------------------------------------------------------
// Phase 1: gate preactivations  pre[m][j] = emb_z[idx[m]] . W_g[j] + b_i + b_h
// M = 64*Cc rows (m = b*Cc + s_local), N = 1024, K = 256. bf16 MFMA 16x16x32.
// Output stored f16.
// ---------------------------------------------------------------------------
__global__ __launch_bounds__(256, 2)
void lstm_xproj(const int* __restrict__ idx, const float* __restrict__ emb,
                const float* __restrict__ w0, const float* __restrict__ w1,
                const float* __restrict__ w2, const float* __restrict__ w3,
                const float* __restrict__ bi0, const float* __restrict__ bi1,
                const float* __restrict__ bi2, const float* __restrict__ bi3,
                const float* __restrict__ bh0, const float* __restrict__ bh1,
                const float* __restrict__ bh2, const float* __restrict__ bh3,
                __half* __restrict__ pre, int s0, int Cc) {
  __shared__ __align__(16) short Ak[4][128][8];  // [kseg][row][8 contiguous k]
  __shared__ __align__(16) short Bk[4][128][8];
  __shared__ int ridx[128];

  const int tid = threadIdx.x;
  const int bm = blockIdx.x, bn = blockIdx.y;
  const int n0 = bn * 128;
  const int g = bn >> 1;            // gate (0..3)
  const int ng = (bn & 1) * 128;    // row base within gate
  const float* wp  = (g == 0) ? w0  : (g == 1) ? w1  : (g == 2) ? w2  : w3;
  const float* bip = (g == 0) ? bi0 : (g == 1) ? bi1 : (g == 2) ? bi2 : bi3;
  const float* bhp = (g == 0) ? bh0 : (g == 1) ? bh1 : (g == 2) ? bh2 : bh3;

  if (tid < 128) {
    int m = bm * 128 + tid;
    int bb = m / Cc;
    int ss = m - bb * Cc;
    ridx[tid] = idx[bb * S_ + s0 + ss];
  }

  float4v z = {0.f, 0.f, 0.f, 0.f};
  float4v acc[4][4];
#pragma unroll
  for (int mi = 0; mi < 4; ++mi)
#pragma unroll
    for (int ni = 0; ni < 4; ++ni) acc[mi][ni] = z;

  const int wv = tid >> 6, lane = tid & 63;
  const int wr = wv >> 1, wc = wv & 1;
  const int lr = lane & 15, ks = lane >> 4;
  const int sr = tid >> 3, seg = tid & 7;

  for (int kt = 0; kt < 8; ++kt) {
    const int k0 = kt * 32;
    __syncthreads();
#pragma unroll
    for (int it = 0; it < 4; ++it) {
      int r = sr + it * 32;
      int tok = ridx[r];
      float4 va = make_float4(0.f, 0.f, 0.f, 0.f);
      if (tok != 0) va = *(const float4*)(emb + (size_t)tok * E_ + k0 + seg * 4);
      short4 sa; sa.x = f2bf(va.x); sa.y = f2bf(va.y); sa.z = f2bf(va.z); sa.w = f2bf(va.w);
      *(short4*)&Ak[seg >> 1][r][(seg & 1) * 4] = sa;
      float4 vb = *(const float4*)(wp + (size_t)(ng + r) * E_ + k0 + seg * 4);
      short4 sb; sb.x = f2bf(vb.x); sb.y = f2bf(vb.y); sb.z = f2bf(vb.z); sb.w = f2bf(vb.w);
      *(short4*)&Bk[seg >> 1][r][(seg & 1) * 4] = sb;
    }
    __syncthreads();
    short8v af[4], bfv[4];
#pragma unroll
    for (int mi = 0; mi < 4; ++mi) af[mi] = *(short8v*)&Ak[ks][wr * 64 + mi * 16 + lr][0];
#pragma unroll
    for (int ni = 0; ni < 4; ++ni) bfv[ni] = *(short8v*)&Bk[ks][wc * 64 + ni * 16 + lr][0];
#pragma unroll
    for (int mi = 0; mi < 4; ++mi)
#pragma unroll
      for (int ni = 0; ni < 4; ++ni)
        acc[mi][ni] = __builtin_amdgcn_mfma_f32_16x16x32_bf16(af[mi], bfv[ni], acc[mi][ni], 0, 0, 0);
  }

#pragma unroll
  for (int ni = 0; ni < 4; ++ni) {
    int jj = ng + wc * 64 + ni * 16 + lr;
    float bias = bip[jj] + bhp[jj];
    int jglob = n0 + wc * 64 + ni * 16 + lr;
#pragma unroll
    for (int mi = 0; mi < 4; ++mi) {
#pragma unroll
      for (int rr = 0; rr < 4; ++rr) {
        int m = bm * 128 + wr * 64 + mi * 16 + (lane >> 4) * 4 + rr;
        pre[(size_t)m * NG + jglob] = __float2half(acc[mi][ni][rr] + bias);
      }
    }
  }
}

// ---------------------------------------------------------------------------
// Phase 2: recurrence. One WG per batch element: 64 WGs x 512 threads,
// static ~129 KB LDS (1 WG/CU, 2 waves/SIMD, full 2048-reg/CU file in use:
// 8 waves x (128 VGPR + 128 AGPR archival) — measured at capacity, R15).
// Thread (jp,q4) owns output rows j0=2jp,j0+1 over K-quarter q4 for all 4
// gates. i/f/g weights archived in 192 V+A dwords; o streams from swizzled
// LDS (0 conflicts, R8). Ping-pong h buffer, x2-unrolled static addresses,
// one light barrier per step (R10+R12). This is the measured optimum of the
// design space explored in R0-R15.
// ---------------------------------------------------------------------------
__global__ __launch_bounds__(512, 2)
void lstm_rec(const __half* __restrict__ pre,
              const float* wh_i, const float* wh_f,
              const float* wh_g, const float* wh_o,
              const float* __restrict__ h0, const float* __restrict__ c0,
              float* out, float* cstate,
              int s0, int Cc) {
  __shared__ uint32_t wlds32[256 * 128];  // o-gate packed f16 pairs (swizzled)
  __shared__ uint32_t hshp[288];          // 2 x 144 quarter-padded h pairs

  const int b = blockIdx.x;
  const int t = threadIdx.x;
  const int lane = t & 63, wave = t >> 6;
  const int q4 = ((lane >> 3) & 1) | ((lane >> 5) << 1);               // 0..3
  const int jp = (wave << 4) | (((lane >> 4) & 1) << 3) | (lane & 7);  // 0..127
  const int j0 = 2 * jp;
  const bool fin = ((lane & 40) == 0);   // q4 == 0: lanes 0-7, 16-23
  const int sw = (jp & 7) << 2;          // o-row XOR swizzle (dwords)

  // --- stage o-gate into LDS, swizzled: col' = col ^ ((row>>1 & 7)<<2) ---
#pragma unroll 8
  for (int i = 0; i < 64; ++i) {
    int idx2 = t + 512 * i;
    int row = idx2 >> 7, col = idx2 & 127;
    float2 v = *(const float2*)(wh_o + 2 * idx2);
    wlds32[row * 128 + (col ^ (((row >> 1) & 7) << 2))] = pkh2(v.x, v.y);
  }

  // --- stage i,f,g rows j0, j0+1, K in [64*q4, 64*q4+64) into registers ---
  uint32_t wI0[32], wI1[32], wF0[32], wF1[32], wG0[32], wG1[32];
  {
    const float4* pI0 = (const float4*)(wh_i + (size_t)j0 * 256 + q4 * 64);
    const float4* pI1 = (const float4*)(wh_i + (size_t)(j0 + 1) * 256 + q4 * 64);
    const float4* pF0 = (const float4*)(wh_f + (size_t)j0 * 256 + q4 * 64);
    const float4* pF1 = (const float4*)(wh_f + (size_t)(j0 + 1) * 256 + q4 * 64);
    const float4* pG0 = (const float4*)(wh_g + (size_t)j0 * 256 + q4 * 64);
    const float4* pG1 = (const float4*)(wh_g + (size_t)(j0 + 1) * 256 + q4 * 64);
#pragma unroll
    for (int k = 0; k < 16; ++k) {
      float4 v;
      v = pI0[k]; wI0[2 * k] = pkh2(v.x, v.y); wI0[2 * k + 1] = pkh2(v.z, v.w);
      v = pI1[k]; wI1[2 * k] = pkh2(v.x, v.y); wI1[2 * k + 1] = pkh2(v.z, v.w);
      v = pF0[k]; wF0[2 * k] = pkh2(v.x, v.y); wF0[2 * k + 1] = pkh2(v.z, v.w);
      v = pF1[k]; wF1[2 * k] = pkh2(v.x, v.y); wF1[2 * k + 1] = pkh2(v.z, v.w);
      v = pG0[k]; wG0[2 * k] = pkh2(v.x, v.y); wG0[2 * k + 1] = pkh2(v.z, v.w);
      v = pG1[k]; wG1[2 * k] = pkh2(v.x, v.y); wG1[2 * k + 1] = pkh2(v.z, v.w);
    }
  }

  // --- init h (buf0) and c (registers, fin lanes) ---
  if (t < 128) {
    float2 hp = (s0 == 0) ? *(const float2*)(h0 + b * H_ + 2 * t)
                          : *(const float2*)(cstate + b * 512 + 256 + 2 * t);
    hshp[(t >> 5) * 36 + (t & 31)] = pkh2(hp.x, hp.y);
  }
  float cR0 = 0.f, cR1 = 0.f, hN0 = 0.f, hN1 = 0.f;
  if (fin) {
    float2 cv = (s0 == 0) ? *(const float2*)(c0 + b * H_ + j0)
                          : *(const float2*)(cstate + b * 512 + j0);
    cR0 = cv.x; cR1 = cv.y;
  }
  __syncthreads();   // staging + h-init complete (full drain once is fine)

  const uint32_t* pb32 = (const uint32_t*)(pre + (size_t)b * (size_t)Cc * NG);
  const uint32_t* wrow0 = wlds32 + (size_t)j0 * 128 + q4 * 32;
  const uint32_t* wrow1 = wrow0 + 128;
  const uint32_t* hqA = hshp + q4 * 36;          // read buf0
  const uint32_t* hqB = hqA + 144;               // read buf1
  uint32_t* hwB = hshp + (jp >> 5) * 36 + (jp & 31);  // write buf0 (body B)
  uint32_t* hwA = hwB + 144;                          // write buf1 (body A)
  float* outp = out + ((size_t)b * S_ + s0) * H_ + j0;

#define HV_(c8)  (*(const uint4*)(hq + (c8) * 4))
#define WO0_(c8) (*(const uint4*)(wrow0 + (((c8) * 4) ^ sw)))
#define WO1_(c8) (*(const uint4*)(wrow1 + (((c8) * 4) ^ sw)))
#define CONS_(c8, hv, wa, wb)                                   \
  aO0 = dot2f(wa.x, hv.x, aO0); aO0 = dot2f(wa.y, hv.y, aO0);   \
  aO0 = dot2f(wa.z, hv.z, aO0); aO0 = dot2f(wa.w, hv.w, aO0);   \
  aO1 = dot2f(wb.x, hv.x, aO1); aO1 = dot2f(wb.y, hv.y, aO1);   \
  aO1 = dot2f(wb.z, hv.z, aO1); aO1 = dot2f(wb.w, hv.w, aO1);   \
  aI0 = dot2f(wI0[(c8) * 4 + 0], hv.x, aI0);                    \
  aI0 = dot2f(wI0[(c8) * 4 + 1], hv.y, aI0);                    \
  aI0 = dot2f(wI0[(c8) * 4 + 2], hv.z, aI0);                    \
  aI0 = dot2f(wI0[(c8) * 4 + 3], hv.w, aI0);                    \
  aI1 = dot2f(wI1[(c8) * 4 + 0], hv.x, aI1);                    \
  aI1 = dot2f(wI1[(c8) * 4 + 1], hv.y, aI1);                    \
  aI1 = dot2f(wI1[(c8) * 4 + 2], hv.z, aI1);                    \
  aI1 = dot2f(wI1[(c8) * 4 + 3], hv.w, aI1);                    \
  aF0 = dot2f(wF0[(c8) * 4 + 0], hv.x, aF0);                    \
  aF0 = dot2f(wF0[(c8) * 4 + 1], hv.y, aF0);                    \
  aF0 = dot2f(wF0[(c8) * 4 + 2], hv.z, aF0);                    \
  aF0 = dot2f(wF0[(c8) * 4 + 3], hv.w, aF0);                    \
  aF1 = dot2f(wF1[(c8) * 4 + 0], hv.x, aF1);                    \
  aF1 = dot2f(wF1[(c8) * 4 + 1], hv.y, aF1);                    \
  aF1 = dot2f(wF1[(c8) * 4 + 2], hv.z, aF1);                    \
  aF1 = dot2f(wF1[(c8) * 4 + 3], hv.w, aF1);                    \
  aG0 = dot2f(wG0[(c8) * 4 + 0], hv.x, aG0);                    \
  aG0 = dot2f(wG0[(c8) * 4 + 1], hv.y, aG0);                    \
  aG0 = dot2f(wG0[(c8) * 4 + 2], hv.z, aG0);                    \
  aG0 = dot2f(wG0[(c8) * 4 + 3], hv.w, aG0);                    \
  aG1 = dot2f(wG1[(c8) * 4 + 0], hv.x, aG1);                    \
  aG1 = dot2f(wG1[(c8) * 4 + 1], hv.y, aG1);                    \
  aG1 = dot2f(wG1[(c8) * 4 + 2], hv.z, aG1);                    \
  aG1 = dot2f(wG1[(c8) * 4 + 3], hv.w, aG1);

// One full LSTM step reading h from HQ, writing new h to HW (other buffer).
// Enters with waA/wbA = o-chunk0, waB/wbB = o-chunk1 already resident.
#define BODY_(HQ, HW)                                                       \
  {                                                                         \
    uint32_t pC0 = 0, pC1 = 0, pC2 = 0, pC3 = 0;                            \
    if (fin) {                                                              \
      const uint32_t* pp = pb32 + (size_t)tl * 512;                         \
      pC0 = pp[jp];       pC1 = pp[128 + jp];                               \
      pC2 = pp[256 + jp]; pC3 = pp[384 + jp];                               \
    }                                                                       \
    const uint32_t* hq = (HQ);                                              \
    float aI0 = 0.f, aI1 = 0.f, aF0 = 0.f, aF1 = 0.f;                       \
    float aG0 = 0.f, aG1 = 0.f, aO0 = 0.f, aO1 = 0.f;                       \
    {                                                                       \
      uint4 hvA = HV_(0), hvB = HV_(1), hvC = HV_(2);                       \
      CONS_(0, hvA, waA, wbA);                                              \
      waA = WO0_(2); wbA = WO1_(2); hvA = HV_(3);                           \
      CONS_(1, hvB, waB, wbB);                                              \
      waB = WO0_(3); wbB = WO1_(3); hvB = HV_(4);                           \
      CONS_(2, hvC, waA, wbA);                                              \
      waA = WO0_(4); wbA = WO1_(4); hvC = HV_(5);                           \
      CONS_(3, hvA, waB, wbB);                                              \
      waB = WO0_(5); wbB = WO1_(5); hvA = HV_(6);                           \
      CONS_(4, hvB, waA, wbA);                                              \
      waA = WO0_(6); wbA = WO1_(6); hvB = HV_(7);                           \
      CONS_(5, hvC, waB, wbB);                                              \
      waB = WO0_(7); wbB = WO1_(7);                                         \
      CONS_(6, hvA, waA, wbA);                                              \
      waA = WO0_(0); wbA = WO1_(0);        /* next-step o chunk 0 */        \
      CONS_(7, hvB, waB, wbB);                                              \
      waB = WO0_(1); wbB = WO1_(1);        /* next-step o chunk 1 */        \
    }                                                                       \
    aI0 = red_q4(aI0); aI1 = red_q4(aI1);                                   \
    aF0 = red_q4(aF0); aF1 = red_q4(aF1);                                   \
    aG0 = red_q4(aG0); aG1 = red_q4(aG1);                                   \
    aO0 = red_q4(aO0); aO1 = red_q4(aO1);                                   \
    if (fin) {                                                              \
      float2 pI = __half22float2(__builtin_bit_cast(__half2, pC0));         \
      float2 pF = __half22float2(__builtin_bit_cast(__half2, pC1));         \
      float2 pG = __half22float2(__builtin_bit_cast(__half2, pC2));         \
      float2 pO = __half22float2(__builtin_bit_cast(__half2, pC3));         \
      float xi0 = aI0 + pI.x, xi1 = aI1 + pI.y;                             \
      float xf0 = aF0 + pF.x, xf1 = aF1 + pF.y;                             \
      float xg0 = aG0 + pG.x, xg1 = aG1 + pG.y;                             \
      float xo0 = aO0 + pO.x, xo1 = aO1 + pO.y;                             \
      cR0 = sigf(xf0) * cR0 + sigf(xi0) * tanhf_fast(xg0);                  \
      cR1 = sigf(xf1) * cR1 + sigf(xi1) * tanhf_fast(xg1);                  \
      hN0 = sigf(xo0) * tanhf_fast(cR0);                                    \
      hN1 = sigf(xo1) * tanhf_fast(cR1);                                    \
      *(float2*)outp = make_float2(hN0, hN1);                               \
      *(HW) = pkh2(hN0, hN1);                                               \
    }                                                                       \
    outp += H_;                                                             \
    ++tl;                                                                   \
    SYNC_LDS();                                                             \
  }

  // prologue: o chunks 0/1 resident before the first body
  uint4 waA = WO0_(0), wbA = WO1_(0);
  uint4 waB = WO0_(1), wbB = WO1_(1);

  int tl = 0;
  while (tl < Cc) {       // Cc is even (launcher guarantees)
    BODY_(hqA, hwA);      // reads buf0, writes buf1
    BODY_(hqB, hwB);      // reads buf1, writes buf0
  }
#undef BODY_
#undef CONS_
#undef WO1_
#undef WO0_
#undef HV_

  if (fin) {
    *(float2*)(cstate + b * 512 + j0) = make_float2(cR0, cR1);
    *(float2*)(cstate + b * 512 + 256 + j0) = make_float2(hN0, hN1);
    if (s0 + Cc == S_) {
      float* hfp = out + (size_t)B_ * S_ * H_;
      float* cfp = hfp + (size_t)B_ * H_;
      *(float2*)(hfp + b * H_ + j0) = make_float2(hN0, hN1);
      *(float2*)(cfp + b * H_ + j0) = make_float2(cR0, cR1);
    }
  }
}

// ---------------------------------------------------------------------------
extern "C" void kernel_launch(void* const* d_in, const int* in_sizes, int n_in,
                              void* d_out, int out_size, void* d_ws, size_t ws_size,
                              hipStream_t stream) {
  (void)in_sizes; (void)n_in; (void)out_size;
  const int* idx = (const int*)d_in[0];
  const float* h0 = (const float*)d_in[1];
  const float* c0 = (const float*)d_in[2];
  const float* emb = (const float*)d_in[3];
  const float* w_ii = (const float*)d_in[4];
  const float* w_if = (const float*)d_in[5];
  const float* w_ig = (const float*)d_in[6];
  const float* w_io = (const float*)d_in[7];
  const float* w_hi = (const float*)d_in[8];
  const float* w_hf = (const float*)d_in[9];
  const float* w_hg = (const float*)d_in[10];
  const float* w_ho = (const float*)d_in[11];
  const float* b_ii = (const float*)d_in[12];
  const float* b_if = (const float*)d_in[13];
  const float* b_ig = (const float*)d_in[14];
  const float* b_io = (const float*)d_in[15];
  const float* b_hi = (const float*)d_in[16];
  const float* b_hf = (const float*)d_in[17];
  const float* b_hg = (const float*)d_in[18];
  const float* b_ho = (const float*)d_in[19];
  float* out = (float*)d_out;

  char* ws = (char*)d_ws;
  float* cstate = (float*)ws;                 // 64 * 512 * 4 = 128 KB (c | h)
  __half* pre = (__half*)(ws + 131072);       // rest: f16 preactivations
  size_t avail = (ws_size > 131072) ? ws_size - 131072 : 0;
  long long cmax = (long long)(avail / ((size_t)B_ * NG * sizeof(__half)));
  int C = (int)((cmax > S_) ? S_ : cmax);
  C &= ~1;
  if (C < 2) C = 2;

  for (int s0 = 0; s0 < S_; s0 += C) {
    int Cc = (S_ - s0 < C) ? (S_ - s0) : C;
    dim3 gg((unsigned)((64 * Cc) / 128), 8);
    lstm_xproj<<<gg, 256, 0, stream>>>(idx, emb, w_ii, w_if, w_ig, w_io,
                                       b_ii, b_if, b_ig, b_io,
                                       b_hi, b_hf, b_hg, b_ho, pre, s0, Cc);
    lstm_rec<<<64, 512, 0, stream>>>(pre, w_hi, w_hf, w_hg, w_ho, h0, c0,
                                     out, cstate, s0, Cc);
  }
}